// Round 8
// baseline (214.643 us; speedup 1.0000x reference)
//
#include <hip/hip_runtime.h>

// Chamfer distance, B=16, N=M=4096, 2-D fp32 points, prefix-length masks.
// d_out: [fwd 16*4096][bwd 16*4096] fp32.
//
// R8: single fused kernel, ZERO workspace. R6==R7 proved the residual was
// structural (16.8MB partials out + cross-XCD re-read + reduce dispatch +
// gaps), not loop micro-structure. New structure: split QUERIES, not points.
// The point stream is wave-uniform -> no LDS needed: uniform float4 loads
// become s_load_dwordx4 (scalar cache), and v_pk_fma_f32 legally takes the
// SGPR pair {x0,x1} as its single SGPR operand. Each lane owns 2 queries
// (one coalesced float4 = 2 float2 queries), loops over ALL the row's points
// in pairs, writes final sqrt+mask directly to d_out.
//   per pair-record/lane: 2 pk (|t|^2 rebuild) + 2q x (2 pk_fma + min3) = 8
//   VALU covering 4 (q,p) pairs -> 2.68e8 pairs * 2.0 /64 *2cyc /1024 SIMD
//   ~ 6.8 us. 1024 waves (1/SIMD) - s_load latency hidden by unroll-4.
// Grid = 32 rows x 32 qchunks exactly; every block writes its 128 outputs
// (Lp==0 -> d2=1e10 -> sqrt=1e5, matching reference BIG semantics).
// Odd Lp: uniform SALU select poisons the high point's x with 1e15.
// No atomics/fences (R3 lesson), no LDS, no __syncthreads, no ws traffic.

typedef float f2 __attribute__((ext_vector_type(2)));

__global__ __launch_bounds__(64) void chamfer_fused(
    const float* __restrict__ src, const float* __restrict__ tgt,
    const int* __restrict__ slen, const int* __restrict__ tlen,
    float* __restrict__ out)
{
    const int blk  = blockIdx.x;       // 1024 = 32 rows x 32 qchunks
    const int row  = blk >> 5;         // dir*16 + b
    const int qc   = blk & 31;         // which 128-query chunk
    const int dir  = row >> 4, b = row & 15;
    const int lane = threadIdx.x;      // 0..63

    const float* Q = dir ? tgt : src;
    const float* P = dir ? src : tgt;
    const int Lq = dir ? tlen[b] : slen[b];   // query-side valid length
    const int Lp = dir ? slen[b] : tlen[b];   // search-side valid length

    // 2 queries per lane via one coalesced float4 load: {qx0,qy0,qx1,qy1}.
    const int q0 = qc * 128 + lane * 2;
    const float4 qq = ((const float4*)(Q + (size_t)b * 8192))[q0 >> 1];

    // Loop-invariant splats: -2q as VGPR pairs (materialized once).
    const f2 mx0 = f2{-2.f * qq.x, -2.f * qq.x};
    const f2 my0 = f2{-2.f * qq.y, -2.f * qq.y};
    const f2 mx1 = f2{-2.f * qq.z, -2.f * qq.z};
    const f2 my1 = f2{-2.f * qq.w, -2.f * qq.w};
    const float s20 = fmaf(qq.x, qq.x, qq.y * qq.y);
    const float s21 = fmaf(qq.z, qq.z, qq.w * qq.w);
    float b0 = 3.0e38f, b1 = 3.0e38f;

    // Uniform point stream: s_load_dwordx4 per pair-record, SALU repack.
    const float4* pts = (const float4*)(P + (size_t)b * 8192);
    const int nrec = (Lp + 1) >> 1;
    #pragma unroll 4
    for (int j = 0; j < nrec; ++j) {
        const float4 pp = pts[j];                       // {x0,y0,x1,y1} uniform
        const float x1 = (2 * j + 1 < Lp) ? pp.z : 1e15f;  // uniform SALU select
        const f2 xp = f2{pp.x, x1};
        const f2 yp = f2{pp.y, pp.w};
        const f2 np = __builtin_elementwise_fma(xp, xp, yp * yp);  // |t|^2 (2 pk)
        f2 v0 = __builtin_elementwise_fma(xp, mx0, np);   // n - 2qx*tx
        v0 = __builtin_elementwise_fma(yp, my0, v0);      // n - 2q.t
        b0 = fminf(b0, fminf(v0.x, v0.y));                // v_min3_f32
        f2 v1 = __builtin_elementwise_fma(xp, mx1, np);
        v1 = __builtin_elementwise_fma(yp, my1, v1);
        b1 = fminf(b1, fminf(v1.x, v1.y));
    }

    // Epilogue: + s2, clamp (commutes with min), sqrt, validity mask.
    const float d0 = (Lp > 0) ? fmaxf(b0 + s20, 0.f) : 1e10f;  // empty set -> BIG
    const float d1 = (Lp > 0) ? fmaxf(b1 + s21, 0.f) : 1e10f;
    float2 r;
    r.x = (q0     < Lq) ? sqrtf(d0) : 0.f;
    r.y = (q0 + 1 < Lq) ? sqrtf(d1) : 0.f;
    ((float2*)(out + (size_t)row * 4096))[q0 >> 1] = r;   // coalesced float2 store
}

extern "C" void kernel_launch(void* const* d_in, const int* in_sizes, int n_in,
                              void* d_out, int out_size, void* d_ws, size_t ws_size,
                              hipStream_t stream) {
    const float* src = (const float*)d_in[0];   // [16,4096,2] f32
    const float* tgt = (const float*)d_in[1];   // [16,4096,2] f32
    const int* slen  = (const int*)d_in[2];     // [16] i32
    const int* tlen  = (const int*)d_in[3];     // [16] i32

    chamfer_fused<<<1024, 64, 0, stream>>>(src, tgt, slen, tlen, (float*)d_out);
}

// Round 9
// 86.938 us; speedup vs baseline: 2.4689x; 2.4689x over previous
//
#include <hip/hip_runtime.h>

// Chamfer distance, B=16, N=M=4096, 2-D fp32 points, prefix-length masks.
// d_out: [fwd 16*4096][bwd 16*4096] fp32.
//
// R9: R8's counters exposed the real residual: VGPR_Count=48 for kernels with
// 64+ live per-query floats (R3-R7) => the NQ=16 arrays were SPILLED to
// scratch; the in-loop scratch traffic is the 2.5x gap (main ~22us vs 5.5us
// VALU model, VALUBusy 36%). Fix: all query state as macro-generated NAMED
// SCALARS (mx2/my2 as explicit f2 register pairs -> v_pk_fma_f32 without
// relying on splat pattern-matching). ~130 VGPR, no spill under (256,2).
// Structure = R7 (best so far): compacted (row, 128-pt chunk) blocks, 16B/pair
// LDS tiles with |t|^2 rebuilt per j (2 pk instrs amortized over 16 queries),
// poisoned coords (1e15) for tail masking, plain partial stores, separate
// reduce kernel (min over nact slices + sqrt + mask). Zero atomics/fences.

typedef float f2 __attribute__((ext_vector_type(2)));

#define FOREACH_Q(F) F(0) F(1) F(2) F(3) F(4) F(5) F(6) F(7) \
                     F(8) F(9) F(10) F(11) F(12) F(13) F(14) F(15)

__global__ __launch_bounds__(256, 2) void chamfer_main(
    const float* __restrict__ src, const float* __restrict__ tgt,
    const int* __restrict__ slen, const int* __restrict__ tlen,
    float* __restrict__ part)   // [32 rows][32 slices][4096] partial mins
{
    __shared__ float4 sh_xy[64];   // {x0,x1,y0,y1} per point-pair (16 B/pair)

    const int g   = blockIdx.x;
    const int tid = threadIdx.x;

    // Compacted work lookup: g -> (row, pc). Uniform SALU.
    int row = -1, pc = 0, Lp = 0, acc = 0;
    #pragma unroll
    for (int rr = 0; rr < 32; ++rr) {
        const int L = (rr < 16) ? tlen[rr] : slen[rr - 16];  // search-side length
        const int n = (L + 127) >> 7;                        // active 128-pt chunks
        if (row < 0 && g < acc + n) { row = rr; pc = g - acc; Lp = L; }
        acc += n;
    }
    if (row < 0) return;             // beyond total active units
    const int dir = row >> 4, b = row & 15;

    const float* Q = dir ? tgt : src;
    const float* P = dir ? src : tgt;

    // Stage 128 points (64 pairs), pair-packed; POISON COORDS for idx >= Lp
    // (1e15^2 dominates any real d2; every active chunk has >=1 valid point).
    if (tid < 64) {
        const int base = pc * 128 + tid * 2;
        const float4 pp = ((const float4*)P)[(b * 4096 + base) >> 1];  // {x0,y0,x1,y1}
        const float x0 = (base + 0 < Lp) ? pp.x : 1e15f;
        const float y0 = (base + 0 < Lp) ? pp.y : 1e15f;
        const float x1 = (base + 1 < Lp) ? pp.z : 1e15f;
        const float y1 = (base + 1 < Lp) ? pp.w : 1e15f;
        sh_xy[tid] = make_float4(x0, x1, y0, y1);            // {x0,x1,y0,y1}
    }
    __syncthreads();

    // 16 queries/thread as NAMED SCALARS (no arrays -> no scratch spill).
    #define DECLQ(k) f2 mx2_##k, my2_##k; float s2_##k, best_##k;
    FOREACH_Q(DECLQ)
    #define INITQ(k) { \
        const float2 q = ((const float2*)Q)[b * 4096 + tid + (k) * 256]; \
        const float mx = -2.f * q.x, my = -2.f * q.y; \
        mx2_##k = f2{mx, mx}; \
        my2_##k = f2{my, my}; \
        s2_##k  = fmaf(q.x, q.x, q.y * q.y); \
        best_##k = 3.0e38f; }
    FOREACH_Q(INITQ)

    // Per point-pair per query: 2 v_pk_fma_f32 + 1 v_min3_f32 (1.5/pair).
    // Per j: 1 ds_read_b128 + 2 packed instrs rebuild n = x^2+y^2.
    #pragma unroll 4
    for (int j = 0; j < 64; ++j) {
        const float4 xy = sh_xy[j];
        const f2 xp = f2{xy.x, xy.y};
        const f2 yp = f2{xy.z, xy.w};
        const f2 np = __builtin_elementwise_fma(xp, xp, yp * yp);
        #define BODYQ(k) { \
            f2 v = __builtin_elementwise_fma(xp, mx2_##k, np); \
            v = __builtin_elementwise_fma(yp, my2_##k, v); \
            best_##k = fminf(best_##k, fminf(v.x, v.y)); }
        FOREACH_Q(BODYQ)
    }

    // Plain coalesced stores to this unit's private slice. No atomics.
    float* slice = part + ((size_t)row * 32 + pc) * 4096;
    #define STOREQ(k) slice[tid + (k) * 256] = fmaxf(best_##k + s2_##k, 0.f);
    FOREACH_Q(STOREQ)
}

__global__ __launch_bounds__(128) void chamfer_reduce(
    const float* __restrict__ part,
    const int* __restrict__ slen, const int* __restrict__ tlen,
    float* __restrict__ out)
{
    const int t  = blockIdx.x * 128 + threadIdx.x;   // 32768 threads, 4 elems each
    const int i4 = t * 4;
    const int row = i4 >> 12;                        // dir*16 + b
    const int dir = row >> 4, b = row & 15;
    const int i   = i4 & 4095;
    const int Lq = dir ? tlen[b] : slen[b];
    const int Lp = dir ? slen[b] : tlen[b];
    const int nact = (Lp + 127) >> 7;                // active slices (block-uniform)

    float4 best = make_float4(1e10f, 1e10f, 1e10f, 1e10f);
    const float4* p = (const float4*)(part + (size_t)row * 32 * 4096 + i);
    #pragma unroll 4
    for (int s = 0; s < nact; ++s) {
        const float4 v = p[(size_t)s * 1024];        // stride 4096 floats
        best.x = fminf(best.x, v.x);
        best.y = fminf(best.y, v.y);
        best.z = fminf(best.z, v.z);
        best.w = fminf(best.w, v.w);
    }
    float4 r;
    r.x = (i + 0 < Lq) ? sqrtf(best.x) : 0.f;        // nact==0 -> sqrt(1e10), matches ref
    r.y = (i + 1 < Lq) ? sqrtf(best.y) : 0.f;
    r.z = (i + 2 < Lq) ? sqrtf(best.z) : 0.f;
    r.w = (i + 3 < Lq) ? sqrtf(best.w) : 0.f;
    ((float4*)out)[t] = r;
}

extern "C" void kernel_launch(void* const* d_in, const int* in_sizes, int n_in,
                              void* d_out, int out_size, void* d_ws, size_t ws_size,
                              hipStream_t stream) {
    const float* src = (const float*)d_in[0];   // [16,4096,2] f32
    const float* tgt = (const float*)d_in[1];   // [16,4096,2] f32
    const int* slen  = (const int*)d_in[2];     // [16] i32
    const int* tlen  = (const int*)d_in[3];     // [16] i32
    float* part = (float*)d_ws;                 // 32 x 32 x 4096 f32 = 16.8 MB

    chamfer_main<<<1024, 256, 0, stream>>>(src, tgt, slen, tlen, part);
    chamfer_reduce<<<256, 128, 0, stream>>>(part, slen, tlen, (float*)d_out);
}